// Round 1
// baseline (253.281 us; speedup 1.0000x reference)
//
#include <hip/hip_runtime.h>

typedef unsigned short u16;
typedef __bf16 bf16x8 __attribute__((ext_vector_type(8)));
typedef float f32x4 __attribute__((ext_vector_type(4)));

#define Bn 4
#define Sn 2048
#define Dn 1024
#define Hn 16
#define HDn 64

__device__ inline u16 f2bf(float f) {
  unsigned u = __builtin_bit_cast(unsigned, f);
  u += 0x7fffu + ((u >> 16) & 1u);
  return (u16)(u >> 16);
}

// async global->LDS DMA, 16B/lane; LDS dest = wave base + lane*16 [m97]
__device__ __forceinline__ void gl2lds16(const u16* g, u16* l) {
  __builtin_amdgcn_global_load_lds(
      (const __attribute__((address_space(1))) unsigned int*)g,
      (__attribute__((address_space(3))) unsigned int*)l, 16, 0, 0);
}

__device__ __forceinline__ float fexp2(float x) {
  return __builtin_amdgcn_exp2f(x);
}

// pack two f32 -> two bf16 (truncating) in one v_perm
__device__ __forceinline__ unsigned pk_bf_trunc(float lo, float hi) {
  return __builtin_amdgcn_perm(__builtin_bit_cast(unsigned, hi),
                               __builtin_bit_cast(unsigned, lo), 0x07060302u);
}

// ---- elementwise fp32 -> bf16 convert (x) ----
__global__ __launch_bounds__(256) void cvt4(const float* __restrict__ in,
                                            u16* __restrict__ out, int n4) {
  int i = blockIdx.x * 256 + threadIdx.x;
  if (i < n4) {
    float4 v = ((const float4*)in)[i];
    ushort4 o;
    o.x = f2bf(v.x); o.y = f2bf(v.y); o.z = f2bf(v.z); o.w = f2bf(v.w);
    ((ushort4*)out)[i] = o;
  }
}

// ---- transpose + convert 4 weights in one launch: out[z][n][k] = in_z[k][n] ----
__global__ __launch_bounds__(256) void tcvt4(const float* __restrict__ w0,
                                             const float* __restrict__ w1,
                                             const float* __restrict__ w2,
                                             const float* __restrict__ w3,
                                             u16* __restrict__ out) {
  __shared__ u16 tile[32][33];
  const float* in = (blockIdx.z == 0) ? w0 : (blockIdx.z == 1) ? w1
                   : (blockIdx.z == 2) ? w2 : w3;
  u16* dst = out + (size_t)blockIdx.z * Dn * Dn;
  int bx = blockIdx.x * 32;
  int by = blockIdx.y * 32;
  int tx = threadIdx.x & 31;
  int ty = threadIdx.x >> 5;
#pragma unroll
  for (int r = 0; r < 32; r += 8)
    tile[ty + r][tx] = f2bf(in[(size_t)(by + ty + r) * Dn + bx + tx]);
  __syncthreads();
#pragma unroll
  for (int r = 0; r < 32; r += 8)
    dst[(size_t)(bx + ty + r) * Dn + by + tx] = tile[tx][ty + r];
}

// ==== fused QKV gemm, 256x256 tile, BK=64, 8-wave 8-phase counted-vmcnt ====
// M=8192, N=3072 (Q|K|V), K=1024.  512 threads = 8 waves in 2(M) x 4(N).
// Per-wave output 128x64. Per buffer, 4 LDS regions of 128 rows x 64 cols:
//   rg0 A-alpha: A rows {0-63, 128-191}   (qr=0 rows of both wave groups)
//   rg1 A-beta : A rows {64-127, 192-255} (qr=1)
//   rg2 B-alpha: B rows {wc*64+0..31}     (qc=0 cols of all 4 wave cols)
//   rg3 B-beta : B rows {wc*64+32..63}    (qc=1)
// Quadrant order per K-tile: (0,0),(0,1),(1,0),(1,1) -> each region's last
// read is 1 phase before its restage; stages run >=4 phases ahead of first
// read, so vmcnt(4) at phases 4 and 8 (2 stages = 4 loads outstanding) is
// provably sufficient. Never vmcnt(0) in steady state.
// LDS swizzle: physical = logical ^ ((row bits1-3)<<4); gl2lds dest stays
// linear, the *global source* is inverse-swizzled (rule #21); ds_read applies
// the same involution -> 2 lanes/bank (conflict-free per m136).
__global__ __launch_bounds__(512, 2) void gemm_qkv(const u16* __restrict__ A,
                                                   const u16* __restrict__ Bt,
                                                   u16* __restrict__ qkb,
                                                   u16* __restrict__ vt,
                                                   float qscale) {
  __shared__ __attribute__((aligned(16))) u16 S[2][4][8192];  // 128 KB

  const int tid = threadIdx.x;
  const int lane = tid & 63;
  const int lcol = lane & 15;
  const int quad = lane >> 4;
  const int wave = tid >> 6;
  const int wr = wave >> 2;  // 0..1 (M)
  const int wc = wave & 3;   // 0..3 (N)

  // XCD-aware bijective swizzle: 384 blocks = 8 XCDs * 48; column-major so
  // each XCD chunk shares B panels (512KB, L2-resident).
  const int bid = blockIdx.x;
  const int swz = (bid & 7) * 48 + (bid >> 3);
  const int bm = (swz & 31) * 256;  // M tile
  const int bn = (swz >> 5) * 256;  // N tile 0..11

  // --- staging source pointers: 4 regions x 2 chunks (8KB each) per thread ---
  const u16* srcp[4][2];
#pragma unroll
  for (int rg = 0; rg < 4; rg++) {
#pragma unroll
    for (int j = 0; j < 2; j++) {
      int o = j * 8192 + tid * 16;            // physical byte offset in region
      int l = o ^ (((o >> 8) & 7) << 4);      // logical byte offset (involution)
      int rho = l >> 7;                       // local row 0..127
      int c2 = (l >> 1) & 63;                 // u16 col 0..63
      int gr;
      if (rg == 0)      gr = bm + (rho & 63) + ((rho >> 6) << 7);
      else if (rg == 1) gr = bm + 64 + (rho & 63) + ((rho >> 6) << 7);
      else if (rg == 2) gr = bn + ((rho >> 5) << 6) + (rho & 31);
      else              gr = bn + ((rho >> 5) << 6) + 32 + (rho & 31);
      const u16* base = (rg < 2) ? A : Bt;
      srcp[rg][j] = base + (size_t)gr * Dn + c2;
    }
  }

  auto stg = [&](int rg, int buf, int tile) {
    if (tile >= 16) return;  // tail guard (only triggers in last iteration)
    const int k0 = tile << 6;
    u16* d = &S[buf][rg][tid * 8];
    gl2lds16(srcp[rg][0] + k0, d);
    gl2lds16(srcp[rg][1] + k0, d + 4096);
  };

  f32x4 acc[8][4];
#pragma unroll
  for (int i = 0; i < 8; i++)
#pragma unroll
    for (int j = 0; j < 4; j++) acc[i][j] = (f32x4){0.f, 0.f, 0.f, 0.f};

  // ds_read swizzled column-byte offsets (row-bits1-3 == lcol bits1-3)
  const int SW = (lcol & 14) << 3;
  const int cs0 = (quad * 16) ^ SW;
  const int cs1 = (64 + quad * 16) ^ SW;

#define PHASE(BUF, QR, QC, STG_STMT, WAIT_STMT)                               \
  {                                                                           \
    const char* Ab = (const char*)&S[BUF][QR][0];                             \
    const char* Bb = (const char*)&S[BUF][2 + QC][0];                         \
    bf16x8 af0[4], af1[4], bf0[2], bf1[2];                                    \
    _Pragma("unroll") for (int mi = 0; mi < 4; mi++) {                        \
      int r = (wr * 64 + mi * 16 + lcol) * 128;                               \
      af0[mi] = *(const bf16x8*)(Ab + (r + cs0));                             \
      af1[mi] = *(const bf16x8*)(Ab + (r + cs1));                             \
    }                                                                         \
    _Pragma("unroll") for (int ni = 0; ni < 2; ni++) {                        \
      int r = (wc * 32 + ni * 16 + lcol) * 128;                               \
      bf0[ni] = *(const bf16x8*)(Bb + (r + cs0));                             \
      bf1[ni] = *(const bf16x8*)(Bb + (r + cs1));                             \
    }                                                                         \
    STG_STMT;                                                                 \
    WAIT_STMT;                                                                \
    __builtin_amdgcn_s_barrier();                                             \
    asm volatile("s_waitcnt lgkmcnt(0)" ::: "memory");                        \
    __builtin_amdgcn_sched_barrier(0);                                        \
    __builtin_amdgcn_s_setprio(1);                                            \
    _Pragma("unroll") for (int mi = 0; mi < 4; mi++)                          \
      _Pragma("unroll") for (int ni = 0; ni < 2; ni++) {                      \
        acc[QR * 4 + mi][QC * 2 + ni] =                                       \
            __builtin_amdgcn_mfma_f32_16x16x32_bf16(                          \
                af0[mi], bf0[ni], acc[QR * 4 + mi][QC * 2 + ni], 0, 0, 0);    \
        acc[QR * 4 + mi][QC * 2 + ni] =                                       \
            __builtin_amdgcn_mfma_f32_16x16x32_bf16(                          \
                af1[mi], bf1[ni], acc[QR * 4 + mi][QC * 2 + ni], 0, 0, 0);    \
      }                                                                       \
    __builtin_amdgcn_s_setprio(0);                                            \
    __builtin_amdgcn_s_barrier();                                             \
  }

  // prologue: tile0 fully -> buf0; tile1 alpha halves -> buf1
  stg(0, 0, 0); stg(2, 0, 0); stg(1, 0, 0); stg(3, 0, 0);
  stg(0, 1, 1); stg(2, 1, 1);
  asm volatile("s_waitcnt vmcnt(4)" ::: "memory");
  __builtin_amdgcn_s_barrier();

#pragma unroll 1
  for (int I = 0; I < 8; ++I) {
    const int t1 = 2 * I + 1, t2 = 2 * I + 2, t3 = 2 * I + 3;
    PHASE(0, 0, 0, stg(1, 1, t1), );
    PHASE(0, 0, 1, stg(3, 1, t1), );
    PHASE(0, 1, 0, stg(0, 0, t2), );
    PHASE(0, 1, 1, stg(2, 0, t2),
          if (I < 7) asm volatile("s_waitcnt vmcnt(4)" ::: "memory");
          else asm volatile("s_waitcnt vmcnt(0)" ::: "memory"));
    PHASE(1, 0, 0, stg(1, 0, t2), );
    PHASE(1, 0, 1, stg(3, 0, t2), );
    PHASE(1, 1, 0, stg(0, 1, t3), );
    PHASE(1, 1, 1, stg(2, 1, t3),
          if (I < 7) asm volatile("s_waitcnt vmcnt(4)" ::: "memory"));
  }
#undef PHASE

  // ---- fused epilogue ----
  const int rb = bm + wr * 128 + quad * 4;
  const int cb = bn + wc * 64 + lcol;
  if (bn >= 2048) {
#pragma unroll
    for (int ai = 0; ai < 8; ai++) {
#pragma unroll
      for (int bj = 0; bj < 4; bj++) {
        int row0 = rb + ((ai >> 2) << 6) + ((ai & 3) << 4);
        int s = row0 & (Sn - 1);
        int bb = row0 >> 11;
        int vcol = cb + ((bj >> 1) << 5) + ((bj & 1) << 4) - 2048;
        int bh = (bb << 4) + (vcol >> 6);
        int hd = vcol & 63;
        unsigned d0 = (unsigned)f2bf(acc[ai][bj][0]) |
                      ((unsigned)f2bf(acc[ai][bj][1]) << 16);
        unsigned d1 = (unsigned)f2bf(acc[ai][bj][2]) |
                      ((unsigned)f2bf(acc[ai][bj][3]) << 16);
        *(uint2*)(vt + ((size_t)bh * HDn + hd) * Sn + s) = (uint2){d0, d1};
      }
    }
  } else {
    const float scale = (bn < 1024) ? qscale : 1.0f;
#pragma unroll
    for (int ai = 0; ai < 8; ai++) {
#pragma unroll
      for (int bj = 0; bj < 4; bj++) {
        int row0 = rb + ((ai >> 2) << 6) + ((ai & 3) << 4);
        int col = cb + ((bj >> 1) << 5) + ((bj & 1) << 4);
#pragma unroll
        for (int r = 0; r < 4; r++)
          qkb[(size_t)(row0 + r) * 2048 + col] = f2bf(acc[ai][bj][r] * scale);
      }
    }
  }
}

// ---- output gemm: [8192 x 1024] fp32+bias, 128x128 tile, BK=64, DBUF ----
__global__ __launch_bounds__(256) void gemm_out(const u16* __restrict__ A,
                                                const u16* __restrict__ Bt,
                                                float* __restrict__ Cout,
                                                const float* __restrict__ bias) {
  __shared__ __attribute__((aligned(16))) u16 As[2][2][128][32];
  __shared__ __attribute__((aligned(16))) u16 Bs[2][2][128][32];
  const int K = Dn;
  const int t = threadIdx.x;
  const int wave = t >> 6;
  const int lane = t & 63;
  const int lcol = lane & 15;
  const int quad = lane >> 4;
  const int wm = (wave >> 1) * 64;
  const int wn = (wave & 1) * 64;
  const int bm = blockIdx.y * 128;
  const int bn = blockIdx.x * 128;

  const int srow = lane >> 2;
  const int sseg = (lane & 3) * 8;
  const u16* a0p = A + (size_t)(bm + wave * 16 + srow) * K + sseg;
  const u16* a1p = a0p + (size_t)64 * K;
  const u16* b0p = Bt + (size_t)(bn + wave * 16 + srow) * K + sseg;
  const u16* b1p = b0p + (size_t)64 * K;
  u16* asl = &As[0][0][0][0] + wave * 512 + lane * 8;
  u16* bsl = &Bs[0][0][0][0] + wave * 512 + lane * 8;

  auto stage = [&](int k0, int d) {
    u16* as = asl + d * 8192;
    u16* bs = bsl + d * 8192;
    gl2lds16(a0p + k0, as);
    gl2lds16(a1p + k0, as + 2048);
    gl2lds16(a0p + k0 + 32, as + 4096);
    gl2lds16(a1p + k0 + 32, as + 6144);
    gl2lds16(b0p + k0, bs);
    gl2lds16(b1p + k0, bs + 2048);
    gl2lds16(b0p + k0 + 32, bs + 4096);
    gl2lds16(b1p + k0 + 32, bs + 6144);
  };

  f32x4 acc[4][4];
#pragma unroll
  for (int i = 0; i < 4; i++)
#pragma unroll
    for (int j = 0; j < 4; j++) acc[i][j] = (f32x4){0.f, 0.f, 0.f, 0.f};

  stage(0, 0);
  int d = 0;
  for (int k0 = 0; k0 < K; k0 += 64, d ^= 1) {
    __syncthreads();
    if (k0 + 64 < K) stage(k0 + 64, d ^ 1);
#pragma unroll
    for (int ks = 0; ks < 2; ks++) {
      bf16x8 af[4], bf[4];
#pragma unroll
      for (int mi = 0; mi < 4; mi++)
        af[mi] = *(const bf16x8*)(&As[d][ks][wm + mi * 16 + lcol][quad * 8]);
#pragma unroll
      for (int ni = 0; ni < 4; ni++)
        bf[ni] = *(const bf16x8*)(&Bs[d][ks][wn + ni * 16 + lcol][quad * 8]);
#pragma unroll
      for (int mi = 0; mi < 4; mi++)
#pragma unroll
        for (int ni = 0; ni < 4; ni++)
          acc[mi][ni] = __builtin_amdgcn_mfma_f32_16x16x32_bf16(af[mi], bf[ni], acc[mi][ni], 0, 0, 0);
    }
  }

#pragma unroll
  for (int mi = 0; mi < 4; mi++) {
#pragma unroll
    for (int ni = 0; ni < 4; ni++) {
#pragma unroll
      for (int r = 0; r < 4; r++) {
        int row = bm + wm + mi * 16 + quad * 4 + r;
        int col = bn + wn + ni * 16 + lcol;
        Cout[(size_t)row * Dn + col] = acc[mi][ni][r] + bias[col];
      }
    }
  }
}

// ---- causal flash attention v5: paired strips for uniform load ----
__global__ __launch_bounds__(256, 2) void attn5(const u16* __restrict__ QK,
                                                const u16* __restrict__ Vt,
                                                u16* __restrict__ ctx) {
  __shared__ __attribute__((aligned(16))) u16 Ks2[2][64][32];
  __shared__ __attribute__((aligned(16))) u16 Vts2[2][64][32];
  __shared__ __attribute__((aligned(16))) u16 Pt[4][32][72];

  const int bh = blockIdx.x;
  const int b = bh >> 4, h = bh & 15;
  const int pair = blockIdx.y;           // 0..7
  const int t = threadIdx.x;
  const int w = t >> 6;
  const int lane = t & 63;
  const int lcol = lane & 15;
  const int quad = lane >> 4;
  const int qw0 = pair * 128 + w * 32;          // short strip wave base
  const int qw1 = (15 - pair) * 128 + w * 32;   // long strip wave base

  const size_t qkbase = ((size_t)b * Sn) * 2048 + h * HDn;
  const size_t obase = ((size_t)b * Sn) * Dn + h * HDn;
  const size_t vbase = ((size_t)bh * HDn) * Sn;

  bf16x8 qf[2][2][2];  // [strip][qb][kc]
#pragma unroll
  for (int si = 0; si < 2; si++) {
    const int qws = si ? qw1 : qw0;
#pragma unroll
    for (int qb = 0; qb < 2; qb++) {
      const u16* qp = QK + qkbase + (size_t)(qws + qb * 16 + lcol) * 2048 + quad * 8;
      qf[si][qb][0] = *(const bf16x8*)qp;
      qf[si][qb][1] = *(const bf16x8*)(qp + 32);
    }
  }

  f32x4 o[2][2][4];  // [strip][qb][nb]
#pragma unroll
  for (int si = 0; si < 2; si++)
#pragma unroll
    for (int qb = 0; qb < 2; qb++)
#pragma unroll
      for (int nb = 0; nb < 4; nb++) o[si][qb][nb] = (f32x4){0.f, 0.f, 0.f, 0.f};
  float lsum[2][2] = {{0.f, 0.f}, {0.f, 0.f}};

  const int srow = lane >> 2;
  const int sseg = (lane & 3) * 8;
  const u16* kp0 = QK + qkbase + 1024 + (size_t)(w * 16 + srow) * 2048 + sseg;
  const u16* vp0 = Vt + vbase + (size_t)(w * 16 + srow) * Sn + sseg;
  u16* ksl0 = &Ks2[0][0][0] + w * 512 + lane * 8;
  u16* ksl1 = ksl0 + 2048;
  u16* vsl0 = &Vts2[0][0][0] + w * 512 + lane * 8;
  u16* vsl1 = vsl0 + 2048;

  auto do_strip = [&](int si, int qw, int j0) {
    f32x4 s[4][2];
#pragma unroll
    for (int mb = 0; mb < 4; mb++) {
      bf16x8 kf0 = *(const bf16x8*)(&Ks2[0][mb * 16 + lcol][quad * 8]);
      bf16x8 kf1 = *(const bf16x8*)(&Ks2[1][mb * 16 + lcol][quad * 8]);
#pragma unroll
      for (int qb = 0; qb < 2; qb++) {
        f32x4 a = (f32x4){0.f, 0.f, 0.f, 0.f};
        a = __builtin_amdgcn_mfma_f32_16x16x32_bf16(kf0, qf[si][qb][0], a, 0, 0, 0);
        a = __builtin_amdgcn_mfma_f32_16x16x32_bf16(kf1, qf[si][qb][1], a, 0, 0, 0);
        s[mb][qb] = a;
      }
    }

    const bool needmask = (j0 + 63 > qw);
#pragma unroll
    for (int qb = 0; qb < 2; qb++) {
      const int qrow = qw + qb * 16 + lcol;
#pragma unroll
      for (int mb = 0; mb < 4; mb++) {
        float p[4];
#pragma unroll
        for (int r = 0; r < 4; r++) p[r] = fexp2(s[mb][qb][r]);
        if (needmask) {
          const int kvb = j0 + mb * 16 + quad * 4;
#pragma unroll
          for (int r = 0; r < 4; r++)
            if (kvb + r > qrow) p[r] = 0.f;
        }
        lsum[si][qb] += (p[0] + p[1]) + (p[2] + p[3]);
        unsigned d0 = pk_bf_trunc(p[0], p[1]);
        unsigned d1 = pk_bf_trunc(p[2], p[3]);
        *(uint2*)(&Pt[w][qb * 16 + lcol][mb * 16 + quad * 4]) = (uint2){d0, d1};
      }
    }

#pragma unroll
    for (int c = 0; c < 2; c++) {
      bf16x8 pf0 = *(const bf16x8*)(&Pt[w][lcol][c * 32 + quad * 8]);
      bf16x8 pf1 = *(const bf16x8*)(&Pt[w][16 + lcol][c * 32 + quad * 8]);
#pragma unroll
      for (int nb = 0; nb < 4; nb++) {
        bf16x8 vf = *(const bf16x8*)(&Vts2[c][nb * 16 + lcol][quad * 8]);
        o[si][0][nb] = __builtin_amdgcn_mfma_f32_16x16x32_bf16(vf, pf0, o[si][0][nb], 0, 0, 0);
        o[si][1][nb] = __builtin_amdgcn_mfma_f32_16x16x32_bf16(vf, pf1, o[si][1][nb], 0, 0, 0);
      }
    }
  };

  const int n_kv = (15 - pair) * 128 + 128;  // long strip upper bound

  for (int j0 = 0; j0 < n_kv; j0 += 64) {
    {
      const u16* kp = kp0 + (size_t)j0 * 2048;
      gl2lds16(kp, ksl0);
      gl2lds16(kp + 32, ksl1);
      const u16* vp = vp0 + j0;
      gl2lds16(vp, vsl0);
      gl2lds16(vp + 32, vsl1);
    }
    __syncthreads();

    if (j0 <= qw1 + 31) do_strip(1, qw1, j0);  // long strip
    if (j0 <= qw0 + 31) do_strip(0, qw0, j0);  // short strip
    __syncthreads();
  }

#pragma unroll
  for (int si = 0; si < 2; si++) {
    const int qws = si ? qw1 : qw0;
#pragma unroll
    for (int qb = 0; qb < 2; qb++) {
      float l = lsum[si][qb];
      l += __shfl_xor(l, 16);
      l += __shfl_xor(l, 32);
      float inv = 1.0f / l;
#pragma unroll
      for (int nb = 0; nb < 4; nb++) {
        unsigned d0 = (unsigned)f2bf(o[si][qb][nb][0] * inv) |
                      ((unsigned)f2bf(o[si][qb][nb][1] * inv) << 16);
        unsigned d1 = (unsigned)f2bf(o[si][qb][nb][2] * inv) |
                      ((unsigned)f2bf(o[si][qb][nb][3] * inv) << 16);
        u16* p = ctx + obase + (size_t)(qws + qb * 16 + lcol) * Dn + nb * 16 + quad * 4;
        *(uint2*)p = (uint2){d0, d1};
      }
    }
  }
}

extern "C" void kernel_launch(void* const* d_in, const int* in_sizes, int n_in,
                              void* d_out, int out_size, void* d_ws, size_t ws_size,
                              hipStream_t stream) {
  const float* x  = (const float*)d_in[0];
  const float* Wq = (const float*)d_in[1];
  const float* Wk = (const float*)d_in[2];
  const float* Wv = (const float*)d_in[3];
  const float* Wo = (const float*)d_in[4];
  const float* bo = (const float*)d_in[5];
  float* out = (float*)d_out;

  const size_t BSD = (size_t)Bn * Sn * Dn;
  const size_t DD = (size_t)Dn * Dn;

  u16* xb    = (u16*)d_ws;           // BSD
  u16* wall  = xb + BSD;             // 4*DD  (Wq^T, Wk^T, Wv^T, Wo^T)
  u16* qkb   = wall + 4 * DD;        // 2*BSD
  u16* vt    = qkb + 2 * BSD;        // BSD
  u16* cb    = vt + BSD;             // BSD

  cvt4<<<(int)(BSD / 4 / 256), 256, 0, stream>>>(x, xb, (int)(BSD / 4));
  tcvt4<<<dim3(Dn / 32, Dn / 32, 4), 256, 0, stream>>>(Wq, Wk, Wv, Wo, wall);

  // fused QKV projection: 256x256 tiles, 8-phase schedule, 384 blocks
  gemm_qkv<<<dim3(384), 512, 0, stream>>>(xb, wall, qkb, vt,
                                          0.125f * 1.44269504f);

  attn5<<<dim3(Bn * Hn, 8), 256, 0, stream>>>(qkb, vt, cb);

  // output projection: 128x128 tiles, 512 blocks, dbuf DMA
  gemm_out<<<dim3(Dn / 128, (Bn * Sn) / 128), 256, 0, stream>>>(cb, wall + 3 * DD, out, bo);
}

// Round 2
// 241.418 us; speedup vs baseline: 1.0491x; 1.0491x over previous
//
#include <hip/hip_runtime.h>

typedef unsigned short u16;
typedef __bf16 bf16x8 __attribute__((ext_vector_type(8)));
typedef float f32x4 __attribute__((ext_vector_type(4)));

#define Bn 4
#define Sn 2048
#define Dn 1024
#define Hn 16
#define HDn 64

__device__ inline u16 f2bf(float f) {
  unsigned u = __builtin_bit_cast(unsigned, f);
  u += 0x7fffu + ((u >> 16) & 1u);
  return (u16)(u >> 16);
}

// async global->LDS DMA, 16B/lane; LDS dest = wave base + lane*16 [m97]
__device__ __forceinline__ void gl2lds16(const u16* g, u16* l) {
  __builtin_amdgcn_global_load_lds(
      (const __attribute__((address_space(1))) unsigned int*)g,
      (__attribute__((address_space(3))) unsigned int*)l, 16, 0, 0);
}

__device__ __forceinline__ float fexp2(float x) {
  return __builtin_amdgcn_exp2f(x);
}

// pack two f32 -> two bf16 (truncating) in one v_perm
__device__ __forceinline__ unsigned pk_bf_trunc(float lo, float hi) {
  return __builtin_amdgcn_perm(__builtin_bit_cast(unsigned, hi),
                               __builtin_bit_cast(unsigned, lo), 0x07060302u);
}

// ---- elementwise fp32 -> bf16 convert (x) ----
__global__ __launch_bounds__(256) void cvt4(const float* __restrict__ in,
                                            u16* __restrict__ out, int n4) {
  int i = blockIdx.x * 256 + threadIdx.x;
  if (i < n4) {
    float4 v = ((const float4*)in)[i];
    ushort4 o;
    o.x = f2bf(v.x); o.y = f2bf(v.y); o.z = f2bf(v.z); o.w = f2bf(v.w);
    ((ushort4*)out)[i] = o;
  }
}

// ---- transpose + convert 4 weights in one launch: out[z][n][k] = in_z[k][n] ----
__global__ __launch_bounds__(256) void tcvt4(const float* __restrict__ w0,
                                             const float* __restrict__ w1,
                                             const float* __restrict__ w2,
                                             const float* __restrict__ w3,
                                             u16* __restrict__ out) {
  __shared__ u16 tile[32][33];
  const float* in = (blockIdx.z == 0) ? w0 : (blockIdx.z == 1) ? w1
                   : (blockIdx.z == 2) ? w2 : w3;
  u16* dst = out + (size_t)blockIdx.z * Dn * Dn;
  int bx = blockIdx.x * 32;
  int by = blockIdx.y * 32;
  int tx = threadIdx.x & 31;
  int ty = threadIdx.x >> 5;
#pragma unroll
  for (int r = 0; r < 32; r += 8)
    tile[ty + r][tx] = f2bf(in[(size_t)(by + ty + r) * Dn + bx + tx]);
  __syncthreads();
#pragma unroll
  for (int r = 0; r < 32; r += 8)
    dst[(size_t)(bx + ty + r) * Dn + by + tx] = tile[tx][ty + r];
}

// ==== fused QKV gemm, 256x256 tile, BK=64, 8-wave, minimal-read phases ====
// M=8192, N=3072 (Q|K|V), K=1024. 512 threads = 8 waves in 2(M) x 4(N).
// Per-wave output 128x64. Per buffer, 4 LDS regions of 128 rows x 64 cols:
//   rg0 A-alpha: A rows {0-63, 128-191}   (rel rows 0-63 of each wr group)
//   rg1 A-beta : A rows {64-127, 192-255} (rel rows 64-127)
//   rg2 B-alpha: B rows {wc*64+0..31}
//   rg3 B-beta : B rows {wc*64+32..63}
// Per K-tile: 4 phases = M-quarters. P0 reads ALL B (8 frags, held in regs
// across the K-tile) + A-quarter0 (4 reads); P1-P3 read only their A-quarter
// (4 reads). 24 ds_read_b128/K-tile/wave (minimum) vs 48 in the QR/QC scheme.
// Stage schedule (tile t stages tile t+1 into buf^1): P0:rg2 P1:rg3 P2:rg0
// P3:rg1. Reads of t+1: {rg2,rg3,rg0} at P0 (covered by vmcnt(2) at t:P3-end,
// 8 outstanding -> oldest 6 landed), rg1 at P2 (covered by vmcnt(4) at
// t+1:P1-end, 6 outstanding -> oldest 2 landed). >=2-phase slack per stage;
// vmcnt(0) only in the t=15 peel.
// LDS swizzle: physical = logical ^ ((row bits1-3)<<4); gl2lds dest linear,
// global source inverse-swizzled (rule #21); ds_read applies same involution
// -> bank-conflict-free (verified: SQ_LDS_BANK_CONFLICT = 0 in R1).
__global__ __launch_bounds__(512, 2) void gemm_qkv(const u16* __restrict__ A,
                                                   const u16* __restrict__ Bt,
                                                   u16* __restrict__ qkb,
                                                   u16* __restrict__ vt,
                                                   float qscale) {
  __shared__ __attribute__((aligned(16))) u16 S[2][4][8192];  // 128 KB

  const int tid = threadIdx.x;
  const int lane = tid & 63;
  const int lcol = lane & 15;
  const int quad = lane >> 4;
  const int wave = tid >> 6;
  const int wr = wave >> 2;  // 0..1 (M)
  const int wc = wave & 3;   // 0..3 (N)

  // XCD swizzle, row-chunked: xcd = bid&7 owns M-tiles xcd*4..xcd*4+3 for all
  // 12 N-tiles -> per-XCD A working set 4x0.5MB = 2MB (L2-fit), B streams.
  const int bid = blockIdx.x;
  const int bm = ((bid & 7) * 4 + ((bid >> 3) & 3)) * 256;  // M tile
  const int bn = (bid >> 5) * 256;                          // N tile 0..11

  // --- staging source pointers: 4 regions x 2 chunks (8KB each) per thread ---
  const u16* srcp[4][2];
#pragma unroll
  for (int rg = 0; rg < 4; rg++) {
#pragma unroll
    for (int j = 0; j < 2; j++) {
      int o = j * 8192 + tid * 16;            // physical byte offset in region
      int l = o ^ (((o >> 8) & 7) << 4);      // logical byte offset (involution)
      int rho = l >> 7;                       // local row 0..127
      int c2 = (l >> 1) & 63;                 // u16 col 0..63
      int gr;
      if (rg == 0)      gr = bm + (rho & 63) + ((rho >> 6) << 7);
      else if (rg == 1) gr = bm + 64 + (rho & 63) + ((rho >> 6) << 7);
      else if (rg == 2) gr = bn + ((rho >> 5) << 6) + (rho & 31);
      else              gr = bn + ((rho >> 5) << 6) + 32 + (rho & 31);
      const u16* base = (rg < 2) ? A : Bt;
      srcp[rg][j] = base + (size_t)gr * Dn + c2;
    }
  }

  auto stg = [&](int rg, int buf, int tile) {
    if (tile >= 16) return;  // tail guard (t=15 only)
    const int k0 = tile << 6;
    u16* d = &S[buf][rg][tid * 8];
    gl2lds16(srcp[rg][0] + k0, d);
    gl2lds16(srcp[rg][1] + k0, d + 4096);
  };

  f32x4 acc[8][4];
#pragma unroll
  for (int i = 0; i < 8; i++)
#pragma unroll
    for (int j = 0; j < 4; j++) acc[i][j] = (f32x4){0.f, 0.f, 0.f, 0.f};

  // ds_read swizzled column-byte offsets (row bits1-3 == lcol bits1-3)
  const int SW = (lcol & 14) << 3;
  const int cs0 = (quad * 16) ^ SW;         // k-step 0 (cols 0-31)
  const int cs1 = (64 + quad * 16) ^ SW;    // k-step 1 (cols 32-63)

  bf16x8 bk0[4], bk1[4];  // B frags, both k-steps, held across the K-tile

#define MFMA16(a, b, c) __builtin_amdgcn_mfma_f32_16x16x32_bf16(a, b, c, 0, 0, 0)

// A frag: quarter Q (0..3), f = frag-in-quarter (0..1), K = k-step
#define ARD(D, Q, F, K)                                                      \
  (*(const bf16x8*)((const char*)&S[D][(Q) >> 1][0] +                        \
      ((wr * 64 + ((Q) & 1) * 32 + (F) * 16 + lcol) * 128 +                  \
       ((K) ? cs1 : cs0))))
// B frag: NI = N-frag (0..3), K = k-step
#define BRD(D, NI, K)                                                        \
  (*(const bf16x8*)((const char*)&S[D][2 + ((NI) >> 1)][0] +                 \
      ((wc * 32 + ((NI) & 1) * 16 + lcol) * 128 + ((K) ? cs1 : cs0))))

#define PHASE(D, T, Q, DO_B, STG_RG, WAIT)                                   \
  {                                                                          \
    bf16x8 a00 = ARD(D, Q, 0, 0), a01 = ARD(D, Q, 0, 1);                     \
    bf16x8 a10 = ARD(D, Q, 1, 0), a11 = ARD(D, Q, 1, 1);                     \
    if (DO_B) {                                                              \
      _Pragma("unroll") for (int ni = 0; ni < 4; ni++) {                     \
        bk0[ni] = BRD(D, ni, 0);                                             \
        bk1[ni] = BRD(D, ni, 1);                                             \
      }                                                                      \
    }                                                                        \
    stg(STG_RG, (D) ^ 1, (T) + 1);                                           \
    WAIT;                                                                    \
    __builtin_amdgcn_s_barrier();                                            \
    asm volatile("s_waitcnt lgkmcnt(0)" ::: "memory");                       \
    __builtin_amdgcn_sched_barrier(0);                                       \
    __builtin_amdgcn_s_setprio(1);                                           \
    _Pragma("unroll") for (int ni = 0; ni < 4; ni++) {                       \
      acc[(Q) * 2][ni] = MFMA16(a00, bk0[ni], acc[(Q) * 2][ni]);             \
      acc[(Q) * 2][ni] = MFMA16(a01, bk1[ni], acc[(Q) * 2][ni]);             \
      acc[(Q) * 2 + 1][ni] = MFMA16(a10, bk0[ni], acc[(Q) * 2 + 1][ni]);     \
      acc[(Q) * 2 + 1][ni] = MFMA16(a11, bk1[ni], acc[(Q) * 2 + 1][ni]);     \
    }                                                                        \
    __builtin_amdgcn_s_setprio(0);                                           \
    __builtin_amdgcn_s_barrier();                                            \
  }

#define TILE(D, T)                                                           \
  PHASE(D, T, 0, 1, 2, )                                                     \
  PHASE(D, T, 1, 0, 3,                                                       \
        if ((T) < 15) asm volatile("s_waitcnt vmcnt(4)" ::: "memory");       \
        else asm volatile("s_waitcnt vmcnt(0)" ::: "memory"))                \
  PHASE(D, T, 2, 0, 0, )                                                     \
  PHASE(D, T, 3, 0, 1, asm volatile("s_waitcnt vmcnt(2)" ::: "memory"))

  // prologue: stage tile0 (all 4 regions) -> buf0; need first 3 landed
  stg(2, 0, 0); stg(3, 0, 0); stg(0, 0, 0); stg(1, 0, 0);
  asm volatile("s_waitcnt vmcnt(2)" ::: "memory");
  __builtin_amdgcn_s_barrier();

#pragma unroll 1
  for (int I = 0; I < 8; ++I) {
    const int T0 = 2 * I, T1 = 2 * I + 1;
    TILE(0, T0)
    TILE(1, T1)
  }
#undef TILE
#undef PHASE
#undef ARD
#undef BRD
#undef MFMA16

  // ---- fused epilogue ----
  const int rb = bm + wr * 128 + quad * 4;
  const int cb = bn + wc * 64 + lcol;
  if (bn >= 2048) {
#pragma unroll
    for (int ai = 0; ai < 8; ai++) {
#pragma unroll
      for (int bj = 0; bj < 4; bj++) {
        int row0 = rb + ((ai >> 2) << 6) + ((ai & 3) << 4);
        int s = row0 & (Sn - 1);
        int bb = row0 >> 11;
        int vcol = cb + ((bj >> 1) << 5) + ((bj & 1) << 4) - 2048;
        int bh = (bb << 4) + (vcol >> 6);
        int hd = vcol & 63;
        unsigned d0 = (unsigned)f2bf(acc[ai][bj][0]) |
                      ((unsigned)f2bf(acc[ai][bj][1]) << 16);
        unsigned d1 = (unsigned)f2bf(acc[ai][bj][2]) |
                      ((unsigned)f2bf(acc[ai][bj][3]) << 16);
        *(uint2*)(vt + ((size_t)bh * HDn + hd) * Sn + s) = (uint2){d0, d1};
      }
    }
  } else {
    const float scale = (bn < 1024) ? qscale : 1.0f;
#pragma unroll
    for (int ai = 0; ai < 8; ai++) {
#pragma unroll
      for (int bj = 0; bj < 4; bj++) {
        int row0 = rb + ((ai >> 2) << 6) + ((ai & 3) << 4);
        int col = cb + ((bj >> 1) << 5) + ((bj & 1) << 4);
#pragma unroll
        for (int r = 0; r < 4; r++)
          qkb[(size_t)(row0 + r) * 2048 + col] = f2bf(acc[ai][bj][r] * scale);
      }
    }
  }
}

// ---- output gemm: [8192 x 1024] fp32+bias, 128x128 tile, BK=64, DBUF ----
__global__ __launch_bounds__(256) void gemm_out(const u16* __restrict__ A,
                                                const u16* __restrict__ Bt,
                                                float* __restrict__ Cout,
                                                const float* __restrict__ bias) {
  __shared__ __attribute__((aligned(16))) u16 As[2][2][128][32];
  __shared__ __attribute__((aligned(16))) u16 Bs[2][2][128][32];
  const int K = Dn;
  const int t = threadIdx.x;
  const int wave = t >> 6;
  const int lane = t & 63;
  const int lcol = lane & 15;
  const int quad = lane >> 4;
  const int wm = (wave >> 1) * 64;
  const int wn = (wave & 1) * 64;
  const int bm = blockIdx.y * 128;
  const int bn = blockIdx.x * 128;

  const int srow = lane >> 2;
  const int sseg = (lane & 3) * 8;
  const u16* a0p = A + (size_t)(bm + wave * 16 + srow) * K + sseg;
  const u16* a1p = a0p + (size_t)64 * K;
  const u16* b0p = Bt + (size_t)(bn + wave * 16 + srow) * K + sseg;
  const u16* b1p = b0p + (size_t)64 * K;
  u16* asl = &As[0][0][0][0] + wave * 512 + lane * 8;
  u16* bsl = &Bs[0][0][0][0] + wave * 512 + lane * 8;

  auto stage = [&](int k0, int d) {
    u16* as = asl + d * 8192;
    u16* bs = bsl + d * 8192;
    gl2lds16(a0p + k0, as);
    gl2lds16(a1p + k0, as + 2048);
    gl2lds16(a0p + k0 + 32, as + 4096);
    gl2lds16(a1p + k0 + 32, as + 6144);
    gl2lds16(b0p + k0, bs);
    gl2lds16(b1p + k0, bs + 2048);
    gl2lds16(b0p + k0 + 32, bs + 4096);
    gl2lds16(b1p + k0 + 32, bs + 6144);
  };

  f32x4 acc[4][4];
#pragma unroll
  for (int i = 0; i < 4; i++)
#pragma unroll
    for (int j = 0; j < 4; j++) acc[i][j] = (f32x4){0.f, 0.f, 0.f, 0.f};

  stage(0, 0);
  int d = 0;
  for (int k0 = 0; k0 < K; k0 += 64, d ^= 1) {
    __syncthreads();
    if (k0 + 64 < K) stage(k0 + 64, d ^ 1);
#pragma unroll
    for (int ks = 0; ks < 2; ks++) {
      bf16x8 af[4], bf[4];
#pragma unroll
      for (int mi = 0; mi < 4; mi++)
        af[mi] = *(const bf16x8*)(&As[d][ks][wm + mi * 16 + lcol][quad * 8]);
#pragma unroll
      for (int ni = 0; ni < 4; ni++)
        bf[ni] = *(const bf16x8*)(&Bs[d][ks][wn + ni * 16 + lcol][quad * 8]);
#pragma unroll
      for (int mi = 0; mi < 4; mi++)
#pragma unroll
        for (int ni = 0; ni < 4; ni++)
          acc[mi][ni] = __builtin_amdgcn_mfma_f32_16x16x32_bf16(af[mi], bf[ni], acc[mi][ni], 0, 0, 0);
    }
  }

#pragma unroll
  for (int mi = 0; mi < 4; mi++) {
#pragma unroll
    for (int ni = 0; ni < 4; ni++) {
#pragma unroll
      for (int r = 0; r < 4; r++) {
        int row = bm + wm + mi * 16 + quad * 4 + r;
        int col = bn + wn + ni * 16 + lcol;
        Cout[(size_t)row * Dn + col] = acc[mi][ni][r] + bias[col];
      }
    }
  }
}

// ---- causal flash attention v5: paired strips for uniform load ----
__global__ __launch_bounds__(256, 2) void attn5(const u16* __restrict__ QK,
                                                const u16* __restrict__ Vt,
                                                u16* __restrict__ ctx) {
  __shared__ __attribute__((aligned(16))) u16 Ks2[2][64][32];
  __shared__ __attribute__((aligned(16))) u16 Vts2[2][64][32];
  __shared__ __attribute__((aligned(16))) u16 Pt[4][32][72];

  const int bh = blockIdx.x;
  const int b = bh >> 4, h = bh & 15;
  const int pair = blockIdx.y;           // 0..7
  const int t = threadIdx.x;
  const int w = t >> 6;
  const int lane = t & 63;
  const int lcol = lane & 15;
  const int quad = lane >> 4;
  const int qw0 = pair * 128 + w * 32;          // short strip wave base
  const int qw1 = (15 - pair) * 128 + w * 32;   // long strip wave base

  const size_t qkbase = ((size_t)b * Sn) * 2048 + h * HDn;
  const size_t obase = ((size_t)b * Sn) * Dn + h * HDn;
  const size_t vbase = ((size_t)bh * HDn) * Sn;

  bf16x8 qf[2][2][2];  // [strip][qb][kc]
#pragma unroll
  for (int si = 0; si < 2; si++) {
    const int qws = si ? qw1 : qw0;
#pragma unroll
    for (int qb = 0; qb < 2; qb++) {
      const u16* qp = QK + qkbase + (size_t)(qws + qb * 16 + lcol) * 2048 + quad * 8;
      qf[si][qb][0] = *(const bf16x8*)qp;
      qf[si][qb][1] = *(const bf16x8*)(qp + 32);
    }
  }

  f32x4 o[2][2][4];  // [strip][qb][nb]
#pragma unroll
  for (int si = 0; si < 2; si++)
#pragma unroll
    for (int qb = 0; qb < 2; qb++)
#pragma unroll
      for (int nb = 0; nb < 4; nb++) o[si][qb][nb] = (f32x4){0.f, 0.f, 0.f, 0.f};
  float lsum[2][2] = {{0.f, 0.f}, {0.f, 0.f}};

  const int srow = lane >> 2;
  const int sseg = (lane & 3) * 8;
  const u16* kp0 = QK + qkbase + 1024 + (size_t)(w * 16 + srow) * 2048 + sseg;
  const u16* vp0 = Vt + vbase + (size_t)(w * 16 + srow) * Sn + sseg;
  u16* ksl0 = &Ks2[0][0][0] + w * 512 + lane * 8;
  u16* ksl1 = ksl0 + 2048;
  u16* vsl0 = &Vts2[0][0][0] + w * 512 + lane * 8;
  u16* vsl1 = vsl0 + 2048;

  auto do_strip = [&](int si, int qw, int j0) {
    f32x4 s[4][2];
#pragma unroll
    for (int mb = 0; mb < 4; mb++) {
      bf16x8 kf0 = *(const bf16x8*)(&Ks2[0][mb * 16 + lcol][quad * 8]);
      bf16x8 kf1 = *(const bf16x8*)(&Ks2[1][mb * 16 + lcol][quad * 8]);
#pragma unroll
      for (int qb = 0; qb < 2; qb++) {
        f32x4 a = (f32x4){0.f, 0.f, 0.f, 0.f};
        a = __builtin_amdgcn_mfma_f32_16x16x32_bf16(kf0, qf[si][qb][0], a, 0, 0, 0);
        a = __builtin_amdgcn_mfma_f32_16x16x32_bf16(kf1, qf[si][qb][1], a, 0, 0, 0);
        s[mb][qb] = a;
      }
    }

    const bool needmask = (j0 + 63 > qw);
#pragma unroll
    for (int qb = 0; qb < 2; qb++) {
      const int qrow = qw + qb * 16 + lcol;
#pragma unroll
      for (int mb = 0; mb < 4; mb++) {
        float p[4];
#pragma unroll
        for (int r = 0; r < 4; r++) p[r] = fexp2(s[mb][qb][r]);
        if (needmask) {
          const int kvb = j0 + mb * 16 + quad * 4;
#pragma unroll
          for (int r = 0; r < 4; r++)
            if (kvb + r > qrow) p[r] = 0.f;
        }
        lsum[si][qb] += (p[0] + p[1]) + (p[2] + p[3]);
        unsigned d0 = pk_bf_trunc(p[0], p[1]);
        unsigned d1 = pk_bf_trunc(p[2], p[3]);
        *(uint2*)(&Pt[w][qb * 16 + lcol][mb * 16 + quad * 4]) = (uint2){d0, d1};
      }
    }

#pragma unroll
    for (int c = 0; c < 2; c++) {
      bf16x8 pf0 = *(const bf16x8*)(&Pt[w][lcol][c * 32 + quad * 8]);
      bf16x8 pf1 = *(const bf16x8*)(&Pt[w][16 + lcol][c * 32 + quad * 8]);
#pragma unroll
      for (int nb = 0; nb < 4; nb++) {
        bf16x8 vf = *(const bf16x8*)(&Vts2[c][nb * 16 + lcol][quad * 8]);
        o[si][0][nb] = __builtin_amdgcn_mfma_f32_16x16x32_bf16(vf, pf0, o[si][0][nb], 0, 0, 0);
        o[si][1][nb] = __builtin_amdgcn_mfma_f32_16x16x32_bf16(vf, pf1, o[si][1][nb], 0, 0, 0);
      }
    }
  };

  const int n_kv = (15 - pair) * 128 + 128;  // long strip upper bound

  for (int j0 = 0; j0 < n_kv; j0 += 64) {
    {
      const u16* kp = kp0 + (size_t)j0 * 2048;
      gl2lds16(kp, ksl0);
      gl2lds16(kp + 32, ksl1);
      const u16* vp = vp0 + j0;
      gl2lds16(vp, vsl0);
      gl2lds16(vp + 32, vsl1);
    }
    __syncthreads();

    if (j0 <= qw1 + 31) do_strip(1, qw1, j0);  // long strip
    if (j0 <= qw0 + 31) do_strip(0, qw0, j0);  // short strip
    __syncthreads();
  }

#pragma unroll
  for (int si = 0; si < 2; si++) {
    const int qws = si ? qw1 : qw0;
#pragma unroll
    for (int qb = 0; qb < 2; qb++) {
      float l = lsum[si][qb];
      l += __shfl_xor(l, 16);
      l += __shfl_xor(l, 32);
      float inv = 1.0f / l;
#pragma unroll
      for (int nb = 0; nb < 4; nb++) {
        unsigned d0 = (unsigned)f2bf(o[si][qb][nb][0] * inv) |
                      ((unsigned)f2bf(o[si][qb][nb][1] * inv) << 16);
        unsigned d1 = (unsigned)f2bf(o[si][qb][nb][2] * inv) |
                      ((unsigned)f2bf(o[si][qb][nb][3] * inv) << 16);
        u16* p = ctx + obase + (size_t)(qws + qb * 16 + lcol) * Dn + nb * 16 + quad * 4;
        *(uint2*)p = (uint2){d0, d1};
      }
    }
  }
}

extern "C" void kernel_launch(void* const* d_in, const int* in_sizes, int n_in,
                              void* d_out, int out_size, void* d_ws, size_t ws_size,
                              hipStream_t stream) {
  const float* x  = (const float*)d_in[0];
  const float* Wq = (const float*)d_in[1];
  const float* Wk = (const float*)d_in[2];
  const float* Wv = (const float*)d_in[3];
  const float* Wo = (const float*)d_in[4];
  const float* bo = (const float*)d_in[5];
  float* out = (float*)d_out;

  const size_t BSD = (size_t)Bn * Sn * Dn;
  const size_t DD = (size_t)Dn * Dn;

  u16* xb    = (u16*)d_ws;           // BSD
  u16* wall  = xb + BSD;             // 4*DD  (Wq^T, Wk^T, Wv^T, Wo^T)
  u16* qkb   = wall + 4 * DD;        // 2*BSD
  u16* vt    = qkb + 2 * BSD;        // BSD
  u16* cb    = vt + BSD;             // BSD

  cvt4<<<(int)(BSD / 4 / 256), 256, 0, stream>>>(x, xb, (int)(BSD / 4));
  tcvt4<<<dim3(Dn / 32, Dn / 32, 4), 256, 0, stream>>>(Wq, Wk, Wv, Wo, wall);

  // fused QKV projection: 256x256 tiles, minimal-read 4-phase schedule
  gemm_qkv<<<dim3(384), 512, 0, stream>>>(xb, wall, qkb, vt,
                                          0.125f * 1.44269504f);

  attn5<<<dim3(Bn * Hn, 8), 256, 0, stream>>>(qkb, vt, cb);

  // output projection: 128x128 tiles, 512 blocks, dbuf DMA
  gemm_out<<<dim3(Dn / 128, (Bn * Sn) / 128), 256, 0, stream>>>(cb, wall + 3 * DD, out, bo);
}